// Round 2
// baseline (9220.544 us; speedup 1.0000x reference)
//
#include <hip/hip_runtime.h>

#define IN_DIM 128
#define HID 64
#define BN 128   // nodes per gemm block
#define KC 32    // k-chunk

__device__ __forceinline__ float relu(float v) { return v > 0.f ? v : 0.f; }

// ---- degree histogram (int) ----
__global__ __launch_bounds__(256) void k_deg(const int* __restrict__ col,
                                             int* __restrict__ degi, int E) {
    int e = blockIdx.x * 256 + threadIdx.x;
    if (e < E) atomicAdd(&degi[col[e]], 1);
}

// ---- dinv[n] = deg>0 ? rsqrt(deg) : 0 ----
__global__ __launch_bounds__(256) void k_dinv(const int* __restrict__ degi,
                                              float* __restrict__ dinv, int N) {
    int n = blockIdx.x * 256 + threadIdx.x;
    if (n < N) {
        int d = degi[n];
        dinv[n] = d > 0 ? rsqrtf((float)d) : 0.f;
    }
}

// ---- scan pass 1: per-block exclusive scan of degi -> start, block sums ----
__global__ __launch_bounds__(256) void k_scan1(const int* __restrict__ degi,
                                               int* __restrict__ start,
                                               int* __restrict__ bsum, int N) {
    __shared__ int s[256];
    const int tid = threadIdx.x;
    const int i = blockIdx.x * 256 + tid;
    const int v = (i < N) ? degi[i] : 0;
    s[tid] = v;
    __syncthreads();
#pragma unroll
    for (int off = 1; off < 256; off <<= 1) {
        int t = (tid >= off) ? s[tid - off] : 0;
        __syncthreads();
        s[tid] += t;
        __syncthreads();
    }
    if (i < N) start[i] = s[tid] - v;
    if (tid == 255) bsum[blockIdx.x] = s[255];
}

// ---- scan pass 2: single block scans block sums (NB <= 512) ----
__global__ __launch_bounds__(512) void k_scan2(int* __restrict__ bsum, int NB) {
    __shared__ int s[512];
    const int tid = threadIdx.x;
    const int v = (tid < NB) ? bsum[tid] : 0;
    s[tid] = v;
    __syncthreads();
#pragma unroll
    for (int off = 1; off < 512; off <<= 1) {
        int t = (tid >= off) ? s[tid - off] : 0;
        __syncthreads();
        s[tid] += t;
        __syncthreads();
    }
    if (tid < NB) bsum[tid] = s[tid] - v;   // exclusive block offsets
}

// ---- scan pass 3: add block offsets; init cursor ----
__global__ __launch_bounds__(256) void k_scan3(int* __restrict__ start,
                                               const int* __restrict__ bsum,
                                               int* __restrict__ cursor, int N) {
    int i = blockIdx.x * 256 + threadIdx.x;
    if (i < N) {
        int v = start[i] + bsum[blockIdx.x];
        start[i] = v;
        cursor[i] = v;
    }
}

// ---- bucket edges by destination: rs[pos]=row, wsrt[pos]=dinv[row]*dinv[col] ----
__global__ __launch_bounds__(256) void k_bucket(const int* __restrict__ row,
                                                const int* __restrict__ col,
                                                const float* __restrict__ dinv,
                                                int* __restrict__ cursor,
                                                int* __restrict__ rs,
                                                float* __restrict__ wsrt, int E) {
    int e = blockIdx.x * 256 + threadIdx.x;
    if (e < E) {
        int r = row[e], c = col[e];
        int pos = atomicAdd(&cursor[c], 1);
        rs[pos] = r;
        wsrt[pos] = dinv[r] * dinv[c];
    }
}

// ---- tiled dual GEMM: O1 = relu(Xcat @ W1 + B1), O2 = Xcat @ W2 ----
// LAYER 1: Xcat = XA (N x 128)
// LAYER 2: Xcat = [XA (N x 64) | relu(XB + CB) (N x 64)]
template <int LAYER>
__global__ __launch_bounds__(256) void k_gemm(const float* __restrict__ XA,
                                              const float* __restrict__ XB,
                                              const float* __restrict__ CB,
                                              const float* __restrict__ W1,
                                              const float* __restrict__ W2,
                                              const float* __restrict__ B1,
                                              float* __restrict__ O1,
                                              float* __restrict__ O2, int N) {
    __shared__ float Xs[KC][BN];   // 16 KB, [k][node] transposed
    __shared__ float Ws[KC][128];  // 16 KB, [k][out] (cols 0-63 W1, 64-127 W2)

    const int tid = threadIdx.x;
    const int n0 = blockIdx.x * BN;
    // staging mapping
    const int sn = tid >> 1;                 // 0..127 node
    const int half = tid & 1;                // low/high 16 k of chunk
    const int ng = min(n0 + sn, N - 1);
    const int m4 = tid & 31;                 // weight quad 0..31
    const int kk0 = tid >> 5;                // 0..7
    // compute mapping
    const int tn = tid & 15;                 // node group
    const int tm = tid >> 4;                 // out group

    float acc[8][8];
#pragma unroll
    for (int i = 0; i < 8; i++)
#pragma unroll
        for (int j = 0; j < 8; j++) acc[i][j] = 0.f;

#pragma unroll
    for (int c = 0; c < 4; ++c) {
        const int k0 = c * KC;
        // --- stage X (transposed, with layer-2 relu+bias transform) ---
        {
            const int kb = k0 + half * 16;   // absolute k of first of 16
            const float* src;
            if (LAYER == 1) {
                src = XA + (size_t)ng * IN_DIM + kb;
            } else {
                src = (kb < 64) ? (XA + (size_t)ng * 64 + kb)
                                : (XB + (size_t)ng * 64 + (kb - 64));
            }
            float4 q0 = *(const float4*)(src + 0);
            float4 q1 = *(const float4*)(src + 4);
            float4 q2 = *(const float4*)(src + 8);
            float4 q3 = *(const float4*)(src + 12);
            if (LAYER == 2 && kb >= 64) {
                const int kb2 = kb - 64;
                const float4 c0 = *(const float4*)(CB + kb2 + 0);
                const float4 c1 = *(const float4*)(CB + kb2 + 4);
                const float4 c2 = *(const float4*)(CB + kb2 + 8);
                const float4 c3 = *(const float4*)(CB + kb2 + 12);
                q0.x = relu(q0.x + c0.x); q0.y = relu(q0.y + c0.y);
                q0.z = relu(q0.z + c0.z); q0.w = relu(q0.w + c0.w);
                q1.x = relu(q1.x + c1.x); q1.y = relu(q1.y + c1.y);
                q1.z = relu(q1.z + c1.z); q1.w = relu(q1.w + c1.w);
                q2.x = relu(q2.x + c2.x); q2.y = relu(q2.y + c2.y);
                q2.z = relu(q2.z + c2.z); q2.w = relu(q2.w + c2.w);
                q3.x = relu(q3.x + c3.x); q3.y = relu(q3.y + c3.y);
                q3.z = relu(q3.z + c3.z); q3.w = relu(q3.w + c3.w);
            }
            const int kl = half * 16;
            Xs[kl + 0][sn] = q0.x;  Xs[kl + 1][sn] = q0.y;
            Xs[kl + 2][sn] = q0.z;  Xs[kl + 3][sn] = q0.w;
            Xs[kl + 4][sn] = q1.x;  Xs[kl + 5][sn] = q1.y;
            Xs[kl + 6][sn] = q1.z;  Xs[kl + 7][sn] = q1.w;
            Xs[kl + 8][sn] = q2.x;  Xs[kl + 9][sn] = q2.y;
            Xs[kl + 10][sn] = q2.z; Xs[kl + 11][sn] = q2.w;
            Xs[kl + 12][sn] = q3.x; Xs[kl + 13][sn] = q3.y;
            Xs[kl + 14][sn] = q3.z; Xs[kl + 15][sn] = q3.w;
        }
        // --- stage W (both matrices side by side) ---
#pragma unroll
        for (int r = 0; r < 4; ++r) {
            const int kk = kk0 + r * 8;
            const int k = k0 + kk;
            float4 wv = (m4 < 16)
                            ? *(const float4*)(W1 + (size_t)k * 64 + m4 * 4)
                            : *(const float4*)(W2 + (size_t)k * 64 + (m4 - 16) * 4);
            *(float4*)&Ws[kk][m4 * 4] = wv;
        }
        __syncthreads();
        // --- compute: 8 nodes x 8 outs per thread ---
#pragma unroll
        for (int k = 0; k < KC; ++k) {
            float a[8], b[8];
            *(float4*)&a[0] = *(const float4*)&Xs[k][tn * 4];
            *(float4*)&a[4] = *(const float4*)&Xs[k][64 + tn * 4];
            *(float4*)&b[0] = *(const float4*)&Ws[k][tm * 4];
            *(float4*)&b[4] = *(const float4*)&Ws[k][64 + tm * 4];
#pragma unroll
            for (int i = 0; i < 8; ++i)
#pragma unroll
                for (int j = 0; j < 8; ++j) acc[i][j] += a[i] * b[j];
        }
        __syncthreads();
    }

    // --- epilogue: cols tm*4..tm*4+3; j 0-3 -> O1 (relu+bias), j 4-7 -> O2 ---
    const float4 bb = *(const float4*)(B1 + tm * 4);
#pragma unroll
    for (int ih = 0; ih < 2; ++ih) {
#pragma unroll
        for (int i = 0; i < 4; ++i) {
            const int n = n0 + ih * 64 + tn * 4 + i;
            if (n < N) {
                const int r = ih * 4 + i;
                float4 o1v = make_float4(relu(acc[r][0] + bb.x), relu(acc[r][1] + bb.y),
                                         relu(acc[r][2] + bb.z), relu(acc[r][3] + bb.w));
                float4 o2v = make_float4(acc[r][4], acc[r][5], acc[r][6], acc[r][7]);
                *(float4*)(O1 + (size_t)n * 64 + tm * 4) = o1v;
                *(float4*)(O2 + (size_t)n * 64 + tm * 4) = o2v;
            }
        }
    }
}

// ---- CSR gather-aggregate, 64 features: wave per destination ----
__global__ __launch_bounds__(256) void k_gather64(const int* __restrict__ start,
                                                  const int* __restrict__ degi,
                                                  const int* __restrict__ rs,
                                                  const float* __restrict__ wsrt,
                                                  const float* __restrict__ H,
                                                  float* __restrict__ AGG, int N) {
    const int lane = threadIdx.x & 63;
    const int d = blockIdx.x * 4 + (threadIdx.x >> 6);
    if (d >= N) return;
    int s = start[d];
    const int e2 = s + degi[d];
    float acc = 0.f;
    for (; s + 1 < e2; s += 2) {
        const int r0 = rs[s], r1 = rs[s + 1];
        const float w0 = wsrt[s], w1 = wsrt[s + 1];
        acc += H[(size_t)r0 * 64 + lane] * w0;
        acc += H[(size_t)r1 * 64 + lane] * w1;
    }
    if (s < e2) acc += H[(size_t)rs[s] * 64 + lane] * wsrt[s];
    AGG[(size_t)d * 64 + lane] = acc;
}

// ---- combine: x7 = x5 + relu(agg2+cb2); out = x7.fc2w + fc2b + c3b; h3 = x7.c3w ----
__global__ __launch_bounds__(256) void k_combine(const float* __restrict__ X5,
                                                 const float* __restrict__ AGG2,
                                                 const float* __restrict__ CB2,
                                                 const float* __restrict__ FC2W,
                                                 const float* __restrict__ FC2B,
                                                 const float* __restrict__ C3W,
                                                 const float* __restrict__ C3B,
                                                 float* __restrict__ H3,
                                                 float* __restrict__ OUT, int N) {
    const int lane = threadIdx.x & 63;
    const int n = blockIdx.x * 4 + (threadIdx.x >> 6);
    if (n >= N) return;
    const size_t o = (size_t)n * 64 + lane;
    const float v = X5[o] + relu(AGG2[o] + CB2[lane]);
    float p9 = v * FC2W[lane];
    float p10 = v * C3W[lane];
#pragma unroll
    for (int s = 32; s >= 1; s >>= 1) {
        p9 += __shfl_xor(p9, s, 64);
        p10 += __shfl_xor(p10, s, 64);
    }
    if (lane == 0) {
        OUT[n] = p9 + FC2B[0] + C3B[0];
        H3[n] = p10;
    }
}

// ---- final CSR gather, 1 feature: thread per destination, out += sum ----
__global__ __launch_bounds__(256) void k_gather1f(const int* __restrict__ start,
                                                  const int* __restrict__ degi,
                                                  const int* __restrict__ rs,
                                                  const float* __restrict__ wsrt,
                                                  const float* __restrict__ H3,
                                                  float* __restrict__ OUT, int N) {
    const int d = blockIdx.x * 256 + threadIdx.x;
    if (d >= N) return;
    int s = start[d];
    const int e2 = s + degi[d];
    float acc = 0.f;
    for (; s + 1 < e2; s += 2) {
        acc += H3[rs[s]] * wsrt[s];
        acc += H3[rs[s + 1]] * wsrt[s + 1];
    }
    if (s < e2) acc += H3[rs[s]] * wsrt[s];
    OUT[d] += acc;
}

extern "C" void kernel_launch(void* const* d_in, const int* in_sizes, int n_in,
                              void* d_out, int out_size, void* d_ws, size_t ws_size,
                              hipStream_t stream) {
    const float* x    = (const float*)d_in[0];
    const float* fcw  = (const float*)d_in[1];
    const float* fcb  = (const float*)d_in[2];
    const float* c1w  = (const float*)d_in[3];
    const float* c1b  = (const float*)d_in[4];
    const float* f1w  = (const float*)d_in[5];
    const float* f1b  = (const float*)d_in[6];
    const float* c2w  = (const float*)d_in[7];
    const float* c2b  = (const float*)d_in[8];
    const float* f2w  = (const float*)d_in[9];
    const float* f2b  = (const float*)d_in[10];
    const float* c3w  = (const float*)d_in[11];
    const float* c3b  = (const float*)d_in[12];
    const int*   ei   = (const int*)d_in[13];

    const int N = in_sizes[0] / IN_DIM;
    const int E = in_sizes[13] / 2;
    const int* row = ei;
    const int* col = ei + E;
    float* out = (float*)d_out;

    // workspace layout with aliasing (peak 4 N*64 buffers)
    const size_t Npad = ((size_t)N + 127) & ~(size_t)127;
    const size_t Epad = ((size_t)E + 127) & ~(size_t)127;
    const size_t NF = (size_t)N * 64;
    int*   degi   = (int*)d_ws;                    // N
    float* dinv   = (float*)(degi + Npad);         // N
    int*   start  = (int*)(dinv + Npad);           // N
    int*   cursor = start + Npad;                  // N
    int*   bsum   = cursor + Npad;                 // 512
    int*   rs     = bsum + 512;                    // E
    float* wsrt   = (float*)(rs + Epad);           // E
    float* x1     = wsrt + Epad;                   // N*64
    float* h1     = x1 + NF;                       // N*64
    float* agg1   = h1 + NF;                       // N*64
    float* x5     = agg1 + NF;                     // N*64
    float* h2     = h1;    // h1 dead after gather1
    float* agg2   = x1;    // x1 dead after gemm2
    float* h3     = agg1;  // agg1 dead after gemm2

    const int gE = (E + 255) / 256;
    const int gN = (N + 255) / 256;
    const int NB = (N + 255) / 256;                // scan blocks (<=512)
    const int gG = (N + BN - 1) / BN;
    const int gW = (N + 3) / 4;

    // --- CSR build ---
    hipMemsetAsync(degi, 0, (size_t)N * sizeof(int), stream);
    k_deg<<<gE, 256, 0, stream>>>(col, degi, E);
    k_dinv<<<gN, 256, 0, stream>>>(degi, dinv, N);
    k_scan1<<<NB, 256, 0, stream>>>(degi, start, bsum, N);
    k_scan2<<<1, 512, 0, stream>>>(bsum, NB);
    k_scan3<<<NB, 256, 0, stream>>>(start, bsum, cursor, N);
    k_bucket<<<gE, 256, 0, stream>>>(row, col, dinv, cursor, rs, wsrt, E);

    // --- layer 1 ---
    k_gemm<1><<<gG, 256, 0, stream>>>(x, nullptr, nullptr, fcw, c1w, fcb, x1, h1, N);
    k_gather64<<<gW, 256, 0, stream>>>(start, degi, rs, wsrt, h1, agg1, N);

    // --- layer 2 ---
    k_gemm<2><<<gG, 256, 0, stream>>>(x1, agg1, c1b, f1w, c2w, f1b, x5, h2, N);
    k_gather64<<<gW, 256, 0, stream>>>(start, degi, rs, wsrt, h2, agg2, N);

    // --- layer 3 ---
    k_combine<<<gW, 256, 0, stream>>>(x5, agg2, c2b, f2w, f2b, c3w, c3b, h3, out, N);
    k_gather1f<<<gN, 256, 0, stream>>>(start, degi, rs, wsrt, h3, out, N);
}

// Round 3
// 520.158 us; speedup vs baseline: 17.7264x; 17.7264x over previous
//
#include <hip/hip_runtime.h>

#define IN_DIM 128
#define HID 64
#define BN 128   // nodes per gemm block tile
#define KC 16    // k-chunk

__device__ __forceinline__ float relu(float v) { return v > 0.f ? v : 0.f; }

// ---- degree histogram (int) ----
__global__ __launch_bounds__(256) void k_deg(const int* __restrict__ col,
                                             int* __restrict__ degi, int E) {
    int e = blockIdx.x * 256 + threadIdx.x;
    if (e < E) atomicAdd(&degi[col[e]], 1);
}

// ---- dinv[n] = deg>0 ? rsqrt(deg) : 0 ----
__global__ __launch_bounds__(256) void k_dinv(const int* __restrict__ degi,
                                              float* __restrict__ dinv, int N) {
    int n = blockIdx.x * 256 + threadIdx.x;
    if (n < N) {
        int d = degi[n];
        dinv[n] = d > 0 ? rsqrtf((float)d) : 0.f;
    }
}

// ---- scan pass 1: per-block exclusive scan of degi -> start, block sums ----
__global__ __launch_bounds__(256) void k_scan1(const int* __restrict__ degi,
                                               int* __restrict__ start,
                                               int* __restrict__ bsum, int N) {
    __shared__ int s[256];
    const int tid = threadIdx.x;
    const int i = blockIdx.x * 256 + tid;
    const int v = (i < N) ? degi[i] : 0;
    s[tid] = v;
    __syncthreads();
    for (int off = 1; off < 256; off <<= 1) {
        int t = (tid >= off) ? s[tid - off] : 0;
        __syncthreads();
        s[tid] += t;
        __syncthreads();
    }
    if (i < N) start[i] = s[tid] - v;
    if (tid == 255) bsum[blockIdx.x] = s[255];
}

// ---- scan pass 2: single block scans block sums (NB <= 512) ----
__global__ __launch_bounds__(512) void k_scan2(int* __restrict__ bsum, int NB) {
    __shared__ int s[512];
    const int tid = threadIdx.x;
    const int v = (tid < NB) ? bsum[tid] : 0;
    s[tid] = v;
    __syncthreads();
    for (int off = 1; off < 512; off <<= 1) {
        int t = (tid >= off) ? s[tid - off] : 0;
        __syncthreads();
        s[tid] += t;
        __syncthreads();
    }
    if (tid < NB) bsum[tid] = s[tid] - v;   // exclusive block offsets
}

// ---- scan pass 3: add block offsets; init cursor ----
__global__ __launch_bounds__(256) void k_scan3(int* __restrict__ start,
                                               const int* __restrict__ bsum,
                                               int* __restrict__ cursor, int N) {
    int i = blockIdx.x * 256 + threadIdx.x;
    if (i < N) {
        int v = start[i] + bsum[blockIdx.x];
        start[i] = v;
        cursor[i] = v;
    }
}

// ---- bucket edges by destination: rs[pos]=row, wsrt[pos]=dinv[row]*dinv[col] ----
__global__ __launch_bounds__(256) void k_bucket(const int* __restrict__ row,
                                                const int* __restrict__ col,
                                                const float* __restrict__ dinv,
                                                int* __restrict__ cursor,
                                                int* __restrict__ rs,
                                                float* __restrict__ wsrt, int E) {
    int e = blockIdx.x * 256 + threadIdx.x;
    if (e < E) {
        int r = row[e], c = col[e];
        int pos = atomicAdd(&cursor[c], 1);
        rs[pos] = r;
        wsrt[pos] = dinv[r] * dinv[c];
    }
}

// ---- tiled dual GEMM: O1 = relu(Xcat @ W1 + B1), O2 = Xcat @ W2 ----
// LAYER 1: Xcat = XA (N x 128)
// LAYER 2: Xcat = [XA (N x 64) | relu(XB + CB) (N x 64)]
// 256 threads, 128-node x 128-col tile, 8 chunks of KC=16.
// Per thread 8x8 accumulators; k-loop unroll capped at 2 to bound VGPRs
// (round-2 lesson: full unroll -> 256 VGPR + 6 GB scratch spill traffic).
template <int LAYER>
__global__ __launch_bounds__(256) void k_gemm(const float* __restrict__ XA,
                                              const float* __restrict__ XB,
                                              const float* __restrict__ CB,
                                              const float* __restrict__ W1,
                                              const float* __restrict__ W2,
                                              const float* __restrict__ B1,
                                              float* __restrict__ O1,
                                              float* __restrict__ O2, int N) {
    __shared__ float Xs[KC][BN];   // 8 KB, [k][node] transposed
    __shared__ float Ws[KC][128];  // 8 KB, [k][out]  (cols 0-63 W1, 64-127 W2)

    const int tid = threadIdx.x;
    const int n0 = blockIdx.x * BN;
    // X staging: thread -> (node, half of k-chunk)
    const int sn = tid >> 1;
    const int khalf = tid & 1;
    const int ng = min(n0 + sn, N - 1);
    // W staging: thread -> (k, col-quad)
    const int wk = tid >> 5;                 // 0..7 (handles wk and wk+8)
    const int wc = tid & 31;                 // col-quad 0..31
    // compute mapping: 16x16 thread grid, each 8 nodes x 8 cols (split 4+4)
    const int tn = tid & 15;
    const int tm = tid >> 4;

    float acc[8][8];
#pragma unroll
    for (int i = 0; i < 8; i++)
#pragma unroll
        for (int j = 0; j < 8; j++) acc[i][j] = 0.f;

    float4 xq0, xq1, wq0, wq1;
    int kb = khalf * 8;   // absolute k of this thread's X stage slice

    // prefetch chunk 0
    {
        const float* sx;
        if (LAYER == 1) sx = XA + (size_t)ng * IN_DIM + kb;
        else sx = (kb < 64) ? (XA + (size_t)ng * 64 + kb)
                            : (XB + (size_t)ng * 64 + (kb - 64));
        xq0 = *(const float4*)(sx + 0);
        xq1 = *(const float4*)(sx + 4);
        const int k1 = wk, k2 = wk + 8;
        if (wc < 16) {
            wq0 = *(const float4*)(W1 + (size_t)k1 * 64 + wc * 4);
            wq1 = *(const float4*)(W1 + (size_t)k2 * 64 + wc * 4);
        } else {
            wq0 = *(const float4*)(W2 + (size_t)k1 * 64 + (wc - 16) * 4);
            wq1 = *(const float4*)(W2 + (size_t)k2 * 64 + (wc - 16) * 4);
        }
    }

    for (int c = 0; c < IN_DIM / KC; ++c) {
        __syncthreads();   // previous compute done before LDS overwrite
        // --- write staged regs to LDS (layer-2 relu+bias applied here) ---
        {
            float4 q0 = xq0, q1 = xq1;
            if (LAYER == 2) {
                const int kba = c * KC + kb;
                if (kba >= 64) {
                    const float4 c0 = *(const float4*)(CB + (kba - 64));
                    const float4 c1 = *(const float4*)(CB + (kba - 64) + 4);
                    q0.x = relu(q0.x + c0.x); q0.y = relu(q0.y + c0.y);
                    q0.z = relu(q0.z + c0.z); q0.w = relu(q0.w + c0.w);
                    q1.x = relu(q1.x + c1.x); q1.y = relu(q1.y + c1.y);
                    q1.z = relu(q1.z + c1.z); q1.w = relu(q1.w + c1.w);
                }
            }
            Xs[kb + 0][sn] = q0.x; Xs[kb + 1][sn] = q0.y;
            Xs[kb + 2][sn] = q0.z; Xs[kb + 3][sn] = q0.w;
            Xs[kb + 4][sn] = q1.x; Xs[kb + 5][sn] = q1.y;
            Xs[kb + 6][sn] = q1.z; Xs[kb + 7][sn] = q1.w;
            *(float4*)&Ws[wk][wc * 4] = wq0;
            *(float4*)&Ws[wk + 8][wc * 4] = wq1;
        }
        __syncthreads();
        // --- issue next chunk's global loads (overlap with compute) ---
        if (c + 1 < IN_DIM / KC) {
            const int kn = (c + 1) * KC + kb;
            const float* sx;
            if (LAYER == 1) sx = XA + (size_t)ng * IN_DIM + kn;
            else sx = (kn < 64) ? (XA + (size_t)ng * 64 + kn)
                                : (XB + (size_t)ng * 64 + (kn - 64));
            xq0 = *(const float4*)(sx + 0);
            xq1 = *(const float4*)(sx + 4);
            const int k1 = (c + 1) * KC + wk, k2 = k1 + 8;
            if (wc < 16) {
                wq0 = *(const float4*)(W1 + (size_t)k1 * 64 + wc * 4);
                wq1 = *(const float4*)(W1 + (size_t)k2 * 64 + wc * 4);
            } else {
                wq0 = *(const float4*)(W2 + (size_t)k1 * 64 + (wc - 16) * 4);
                wq1 = *(const float4*)(W2 + (size_t)k2 * 64 + (wc - 16) * 4);
            }
        }
        // --- compute: 8 nodes x 8 cols per thread ---
#pragma unroll 2
        for (int k = 0; k < KC; ++k) {
            const float4 aLo = *(const float4*)&Xs[k][tn * 4];
            const float4 aHi = *(const float4*)&Xs[k][64 + tn * 4];
            const float4 bLo = *(const float4*)&Ws[k][tm * 4];
            const float4 bHi = *(const float4*)&Ws[k][64 + tm * 4];
            const float b0 = bLo.x, b1 = bLo.y, b2 = bLo.z, b3 = bLo.w;
            const float b4 = bHi.x, b5 = bHi.y, b6 = bHi.z, b7 = bHi.w;
#define FMA_ROW(i, ai)                                                   \
    acc[i][0] += (ai) * b0; acc[i][1] += (ai) * b1;                      \
    acc[i][2] += (ai) * b2; acc[i][3] += (ai) * b3;                      \
    acc[i][4] += (ai) * b4; acc[i][5] += (ai) * b5;                      \
    acc[i][6] += (ai) * b6; acc[i][7] += (ai) * b7;
            FMA_ROW(0, aLo.x) FMA_ROW(1, aLo.y) FMA_ROW(2, aLo.z) FMA_ROW(3, aLo.w)
            FMA_ROW(4, aHi.x) FMA_ROW(5, aHi.y) FMA_ROW(6, aHi.z) FMA_ROW(7, aHi.w)
#undef FMA_ROW
        }
    }

    // --- epilogue: j 0-3 -> O1 (relu+bias at col tm*4), j 4-7 -> O2 ---
    const float4 bb = *(const float4*)(B1 + tm * 4);
#pragma unroll
    for (int ih = 0; ih < 2; ++ih) {
#pragma unroll
        for (int i = 0; i < 4; ++i) {
            const int n = n0 + ih * 64 + tn * 4 + i;
            if (n < N) {
                const int r = ih * 4 + i;
                float4 o1v = make_float4(relu(acc[r][0] + bb.x), relu(acc[r][1] + bb.y),
                                         relu(acc[r][2] + bb.z), relu(acc[r][3] + bb.w));
                float4 o2v = make_float4(acc[r][4], acc[r][5], acc[r][6], acc[r][7]);
                *(float4*)(O1 + (size_t)n * 64 + tm * 4) = o1v;
                *(float4*)(O2 + (size_t)n * 64 + tm * 4) = o2v;
            }
        }
    }
}

// ---- CSR gather-aggregate, 64 features: wave per destination ----
__global__ __launch_bounds__(256) void k_gather64(const int* __restrict__ start,
                                                  const int* __restrict__ degi,
                                                  const int* __restrict__ rs,
                                                  const float* __restrict__ wsrt,
                                                  const float* __restrict__ H,
                                                  float* __restrict__ AGG, int N) {
    const int lane = threadIdx.x & 63;
    const int d = blockIdx.x * 4 + (threadIdx.x >> 6);
    if (d >= N) return;
    int s = start[d];
    const int e2 = s + degi[d];
    float acc = 0.f;
    for (; s + 1 < e2; s += 2) {
        const int r0 = rs[s], r1 = rs[s + 1];
        const float w0 = wsrt[s], w1 = wsrt[s + 1];
        acc += H[(size_t)r0 * 64 + lane] * w0;
        acc += H[(size_t)r1 * 64 + lane] * w1;
    }
    if (s < e2) acc += H[(size_t)rs[s] * 64 + lane] * wsrt[s];
    AGG[(size_t)d * 64 + lane] = acc;
}

// ---- combine: x7 = x5 + relu(agg2+cb2); out = x7.fc2w + fc2b + c3b; h3 = x7.c3w ----
__global__ __launch_bounds__(256) void k_combine(const float* __restrict__ X5,
                                                 const float* __restrict__ AGG2,
                                                 const float* __restrict__ CB2,
                                                 const float* __restrict__ FC2W,
                                                 const float* __restrict__ FC2B,
                                                 const float* __restrict__ C3W,
                                                 const float* __restrict__ C3B,
                                                 float* __restrict__ H3,
                                                 float* __restrict__ OUT, int N) {
    const int lane = threadIdx.x & 63;
    const int n = blockIdx.x * 4 + (threadIdx.x >> 6);
    if (n >= N) return;
    const size_t o = (size_t)n * 64 + lane;
    const float v = X5[o] + relu(AGG2[o] + CB2[lane]);
    float p9 = v * FC2W[lane];
    float p10 = v * C3W[lane];
#pragma unroll
    for (int s = 32; s >= 1; s >>= 1) {
        p9 += __shfl_xor(p9, s, 64);
        p10 += __shfl_xor(p10, s, 64);
    }
    if (lane == 0) {
        OUT[n] = p9 + FC2B[0] + C3B[0];
        H3[n] = p10;
    }
}

// ---- final CSR gather, 1 feature: thread per destination, out += sum ----
__global__ __launch_bounds__(256) void k_gather1f(const int* __restrict__ start,
                                                  const int* __restrict__ degi,
                                                  const int* __restrict__ rs,
                                                  const float* __restrict__ wsrt,
                                                  const float* __restrict__ H3,
                                                  float* __restrict__ OUT, int N) {
    const int d = blockIdx.x * 256 + threadIdx.x;
    if (d >= N) return;
    int s = start[d];
    const int e2 = s + degi[d];
    float acc = 0.f;
    for (; s + 1 < e2; s += 2) {
        acc += H3[rs[s]] * wsrt[s];
        acc += H3[rs[s + 1]] * wsrt[s + 1];
    }
    if (s < e2) acc += H3[rs[s]] * wsrt[s];
    OUT[d] += acc;
}

extern "C" void kernel_launch(void* const* d_in, const int* in_sizes, int n_in,
                              void* d_out, int out_size, void* d_ws, size_t ws_size,
                              hipStream_t stream) {
    const float* x    = (const float*)d_in[0];
    const float* fcw  = (const float*)d_in[1];
    const float* fcb  = (const float*)d_in[2];
    const float* c1w  = (const float*)d_in[3];
    const float* c1b  = (const float*)d_in[4];
    const float* f1w  = (const float*)d_in[5];
    const float* f1b  = (const float*)d_in[6];
    const float* c2w  = (const float*)d_in[7];
    const float* c2b  = (const float*)d_in[8];
    const float* f2w  = (const float*)d_in[9];
    const float* f2b  = (const float*)d_in[10];
    const float* c3w  = (const float*)d_in[11];
    const float* c3b  = (const float*)d_in[12];
    const int*   ei   = (const int*)d_in[13];

    const int N = in_sizes[0] / IN_DIM;
    const int E = in_sizes[13] / 2;
    const int* row = ei;
    const int* col = ei + E;
    float* out = (float*)d_out;

    // workspace layout with aliasing (peak 4 N*64 buffers)
    const size_t Npad = ((size_t)N + 127) & ~(size_t)127;
    const size_t Epad = ((size_t)E + 127) & ~(size_t)127;
    const size_t NF = (size_t)N * 64;
    int*   degi   = (int*)d_ws;                    // N
    float* dinv   = (float*)(degi + Npad);         // N
    int*   start  = (int*)(dinv + Npad);           // N
    int*   cursor = start + Npad;                  // N
    int*   bsum   = cursor + Npad;                 // 512
    int*   rs     = bsum + 512;                    // E
    float* wsrt   = (float*)(rs + Epad);           // E
    float* x1     = wsrt + Epad;                   // N*64
    float* h1     = x1 + NF;                       // N*64
    float* agg1   = h1 + NF;                       // N*64
    float* x5     = agg1 + NF;                     // N*64
    float* h2     = h1;    // h1 dead after gather1
    float* agg2   = x1;    // x1 dead after gemm2
    float* h3     = agg1;  // agg1 dead after gemm2

    const int gE = (E + 255) / 256;
    const int gN = (N + 255) / 256;
    const int NB = (N + 255) / 256;                // scan blocks (<=512)
    const int gG = (N + BN - 1) / BN;
    const int gW = (N + 3) / 4;

    // --- CSR build ---
    hipMemsetAsync(degi, 0, (size_t)N * sizeof(int), stream);
    k_deg<<<gE, 256, 0, stream>>>(col, degi, E);
    k_dinv<<<gN, 256, 0, stream>>>(degi, dinv, N);
    k_scan1<<<NB, 256, 0, stream>>>(degi, start, bsum, N);
    k_scan2<<<1, 512, 0, stream>>>(bsum, NB);
    k_scan3<<<NB, 256, 0, stream>>>(start, bsum, cursor, N);
    k_bucket<<<gE, 256, 0, stream>>>(row, col, dinv, cursor, rs, wsrt, E);

    // --- layer 1 ---
    k_gemm<1><<<gG, 256, 0, stream>>>(x, nullptr, nullptr, fcw, c1w, fcb, x1, h1, N);
    k_gather64<<<gW, 256, 0, stream>>>(start, degi, rs, wsrt, h1, agg1, N);

    // --- layer 2 ---
    k_gemm<2><<<gG, 256, 0, stream>>>(x1, agg1, c1b, f1w, c2w, f1b, x5, h2, N);
    k_gather64<<<gW, 256, 0, stream>>>(start, degi, rs, wsrt, h2, agg2, N);

    // --- layer 3 ---
    k_combine<<<gW, 256, 0, stream>>>(x5, agg2, c2b, f2w, f2b, c3w, c3b, h3, out, N);
    k_gather1f<<<gN, 256, 0, stream>>>(start, degi, rs, wsrt, h3, out, N);
}

// Round 4
// 473.935 us; speedup vs baseline: 19.4553x; 1.0975x over previous
//
#include <hip/hip_runtime.h>

#define IN_DIM 128
#define HID 64
#define BN 128    // nodes per gemm block tile
#define KC 16     // gemm k-chunk
#define CH 16384  // edges per bucket chunk

__device__ __forceinline__ float relu(float v) { return v > 0.f ? v : 0.f; }

// ---- degree histogram (int) ----
__global__ __launch_bounds__(256) void k_deg(const int* __restrict__ col,
                                             int* __restrict__ degi, int E) {
    int e = blockIdx.x * 256 + threadIdx.x;
    if (e < E) atomicAdd(&degi[col[e]], 1);
}

// ---- scan pass 1 (+ fused dinv): per-block exclusive scan of degi ----
__global__ __launch_bounds__(256) void k_scan1(const int* __restrict__ degi,
                                               float* __restrict__ dinv,
                                               int* __restrict__ start,
                                               int* __restrict__ bsum, int N) {
    __shared__ int s[256];
    const int tid = threadIdx.x;
    const int i = blockIdx.x * 256 + tid;
    const int v = (i < N) ? degi[i] : 0;
    if (i < N) dinv[i] = v > 0 ? rsqrtf((float)v) : 0.f;
    s[tid] = v;
    __syncthreads();
    for (int off = 1; off < 256; off <<= 1) {
        int t = (tid >= off) ? s[tid - off] : 0;
        __syncthreads();
        s[tid] += t;
        __syncthreads();
    }
    if (i < N) start[i] = s[tid] - v;
    if (tid == 255) bsum[blockIdx.x] = s[255];
}

// ---- scan pass 2: single block scans block sums (NB <= 512) ----
__global__ __launch_bounds__(512) void k_scan2(int* __restrict__ bsum, int NB) {
    __shared__ int s[512];
    const int tid = threadIdx.x;
    const int v = (tid < NB) ? bsum[tid] : 0;
    s[tid] = v;
    __syncthreads();
    for (int off = 1; off < 512; off <<= 1) {
        int t = (tid >= off) ? s[tid - off] : 0;
        __syncthreads();
        s[tid] += t;
        __syncthreads();
    }
    if (tid < NB) bsum[tid] = s[tid] - v;   // exclusive block offsets
}

// ---- scan pass 3: add block offsets; init cursor ----
__global__ __launch_bounds__(256) void k_scan3(int* __restrict__ start,
                                               const int* __restrict__ bsum,
                                               int* __restrict__ cursor, int N) {
    int i = blockIdx.x * 256 + threadIdx.x;
    if (i < N) {
        int v = start[i] + bsum[blockIdx.x];
        start[i] = v;
        cursor[i] = v;
    }
}

// ---- bucket edges by destination, range-partitioned ----
// block b: edge chunk b/8, keeps only destinations in range (b&7).
// Packs (row, norm) as int2 -> single 8B scattered stream; writes to each
// CSR slice come from 1/8 of blocks (round-robin XCD heuristic) so cache
// lines fill before eviction (round-3: 121 MB WRITE_SIZE from 10 MB payload).
__global__ __launch_bounds__(256) void k_bucket(const int* __restrict__ row,
                                                const int* __restrict__ col,
                                                const float* __restrict__ dinv,
                                                int* __restrict__ cursor,
                                                int2* __restrict__ rw,
                                                int E, int RB, int N) {
    const int chunk = blockIdx.x >> 3;
    const int r = blockIdx.x & 7;
    const int lo = r * RB;
    const int hi = min(lo + RB, N);
    const int e1 = min(chunk * CH + CH, E);
    for (int e = chunk * CH + threadIdx.x; e < e1; e += 256) {
        const int c = col[e];
        if (c >= lo && c < hi) {
            const int rr = row[e];
            const int pos = atomicAdd(&cursor[c], 1);
            int2 v;
            v.x = rr;
            v.y = __float_as_int(dinv[rr] * dinv[c]);
            rw[pos] = v;
        }
    }
}

// ---- tiled dual GEMM: O1 = relu(Xcat @ W1 + B1), O2 = Xcat @ W2 ----
// LAYER 1: Xcat = XA (N x 128); LAYER 2: Xcat = [XA | relu(XB + CB)]
template <int LAYER>
__global__ __launch_bounds__(256) void k_gemm(const float* __restrict__ XA,
                                              const float* __restrict__ XB,
                                              const float* __restrict__ CB,
                                              const float* __restrict__ W1,
                                              const float* __restrict__ W2,
                                              const float* __restrict__ B1,
                                              float* __restrict__ O1,
                                              float* __restrict__ O2, int N) {
    __shared__ float Xs[KC][BN];   // 8 KB, [k][node]
    __shared__ float Ws[KC][128];  // 8 KB, [k][out] (0-63 W1, 64-127 W2)

    const int tid = threadIdx.x;
    const int n0 = blockIdx.x * BN;
    const int sn = tid >> 1;
    const int khalf = tid & 1;
    const int ng = min(n0 + sn, N - 1);
    const int wk = tid >> 5;
    const int wc = tid & 31;
    const int tn = tid & 15;
    const int tm = tid >> 4;

    float acc[8][8];
#pragma unroll
    for (int i = 0; i < 8; i++)
#pragma unroll
        for (int j = 0; j < 8; j++) acc[i][j] = 0.f;

    float4 xq0, xq1, wq0, wq1;
    int kb = khalf * 8;

    {
        const float* sx;
        if (LAYER == 1) sx = XA + (size_t)ng * IN_DIM + kb;
        else sx = (kb < 64) ? (XA + (size_t)ng * 64 + kb)
                            : (XB + (size_t)ng * 64 + (kb - 64));
        xq0 = *(const float4*)(sx + 0);
        xq1 = *(const float4*)(sx + 4);
        if (wc < 16) {
            wq0 = *(const float4*)(W1 + (size_t)wk * 64 + wc * 4);
            wq1 = *(const float4*)(W1 + (size_t)(wk + 8) * 64 + wc * 4);
        } else {
            wq0 = *(const float4*)(W2 + (size_t)wk * 64 + (wc - 16) * 4);
            wq1 = *(const float4*)(W2 + (size_t)(wk + 8) * 64 + (wc - 16) * 4);
        }
    }

    for (int c = 0; c < IN_DIM / KC; ++c) {
        __syncthreads();
        {
            float4 q0 = xq0, q1 = xq1;
            if (LAYER == 2) {
                const int kba = c * KC + kb;
                if (kba >= 64) {
                    const float4 c0 = *(const float4*)(CB + (kba - 64));
                    const float4 c1 = *(const float4*)(CB + (kba - 64) + 4);
                    q0.x = relu(q0.x + c0.x); q0.y = relu(q0.y + c0.y);
                    q0.z = relu(q0.z + c0.z); q0.w = relu(q0.w + c0.w);
                    q1.x = relu(q1.x + c1.x); q1.y = relu(q1.y + c1.y);
                    q1.z = relu(q1.z + c1.z); q1.w = relu(q1.w + c1.w);
                }
            }
            Xs[kb + 0][sn] = q0.x; Xs[kb + 1][sn] = q0.y;
            Xs[kb + 2][sn] = q0.z; Xs[kb + 3][sn] = q0.w;
            Xs[kb + 4][sn] = q1.x; Xs[kb + 5][sn] = q1.y;
            Xs[kb + 6][sn] = q1.z; Xs[kb + 7][sn] = q1.w;
            *(float4*)&Ws[wk][wc * 4] = wq0;
            *(float4*)&Ws[wk + 8][wc * 4] = wq1;
        }
        __syncthreads();
        if (c + 1 < IN_DIM / KC) {
            const int kn = (c + 1) * KC + kb;
            const float* sx;
            if (LAYER == 1) sx = XA + (size_t)ng * IN_DIM + kn;
            else sx = (kn < 64) ? (XA + (size_t)ng * 64 + kn)
                                : (XB + (size_t)ng * 64 + (kn - 64));
            xq0 = *(const float4*)(sx + 0);
            xq1 = *(const float4*)(sx + 4);
            const int k1 = (c + 1) * KC + wk, k2 = k1 + 8;
            if (wc < 16) {
                wq0 = *(const float4*)(W1 + (size_t)k1 * 64 + wc * 4);
                wq1 = *(const float4*)(W1 + (size_t)k2 * 64 + wc * 4);
            } else {
                wq0 = *(const float4*)(W2 + (size_t)k1 * 64 + (wc - 16) * 4);
                wq1 = *(const float4*)(W2 + (size_t)k2 * 64 + (wc - 16) * 4);
            }
        }
#pragma unroll 2
        for (int k = 0; k < KC; ++k) {
            const float4 aLo = *(const float4*)&Xs[k][tn * 4];
            const float4 aHi = *(const float4*)&Xs[k][64 + tn * 4];
            const float4 bLo = *(const float4*)&Ws[k][tm * 4];
            const float4 bHi = *(const float4*)&Ws[k][64 + tm * 4];
            const float b0 = bLo.x, b1 = bLo.y, b2 = bLo.z, b3 = bLo.w;
            const float b4 = bHi.x, b5 = bHi.y, b6 = bHi.z, b7 = bHi.w;
#define FMA_ROW(i, ai)                                                   \
    acc[i][0] += (ai) * b0; acc[i][1] += (ai) * b1;                      \
    acc[i][2] += (ai) * b2; acc[i][3] += (ai) * b3;                      \
    acc[i][4] += (ai) * b4; acc[i][5] += (ai) * b5;                      \
    acc[i][6] += (ai) * b6; acc[i][7] += (ai) * b7;
            FMA_ROW(0, aLo.x) FMA_ROW(1, aLo.y) FMA_ROW(2, aLo.z) FMA_ROW(3, aLo.w)
            FMA_ROW(4, aHi.x) FMA_ROW(5, aHi.y) FMA_ROW(6, aHi.z) FMA_ROW(7, aHi.w)
#undef FMA_ROW
        }
    }

    const float4 bb = *(const float4*)(B1 + tm * 4);
#pragma unroll
    for (int ih = 0; ih < 2; ++ih) {
#pragma unroll
        for (int i = 0; i < 4; ++i) {
            const int n = n0 + ih * 64 + tn * 4 + i;
            if (n < N) {
                const int r = ih * 4 + i;
                float4 o1v = make_float4(relu(acc[r][0] + bb.x), relu(acc[r][1] + bb.y),
                                         relu(acc[r][2] + bb.z), relu(acc[r][3] + bb.w));
                float4 o2v = make_float4(acc[r][4], acc[r][5], acc[r][6], acc[r][7]);
                *(float4*)(O1 + (size_t)n * 64 + tm * 4) = o1v;
                *(float4*)(O2 + (size_t)n * 64 + tm * 4) = o2v;
            }
        }
    }
}

// ---- CSR gather-aggregate, 64 features: wave per destination ----
__global__ __launch_bounds__(256) void k_gather64(const int* __restrict__ start,
                                                  const int* __restrict__ degi,
                                                  const int2* __restrict__ rw,
                                                  const float* __restrict__ H,
                                                  float* __restrict__ AGG, int N) {
    const int lane = threadIdx.x & 63;
    const int d = blockIdx.x * 4 + (threadIdx.x >> 6);
    if (d >= N) return;
    int s = start[d];
    const int e2 = s + degi[d];
    float acc = 0.f;
    for (; s + 3 < e2; s += 4) {
        const int2 a = rw[s], b = rw[s + 1], c = rw[s + 2], dd = rw[s + 3];
        acc += H[(size_t)a.x * 64 + lane] * __int_as_float(a.y);
        acc += H[(size_t)b.x * 64 + lane] * __int_as_float(b.y);
        acc += H[(size_t)c.x * 64 + lane] * __int_as_float(c.y);
        acc += H[(size_t)dd.x * 64 + lane] * __int_as_float(dd.y);
    }
    for (; s < e2; ++s) {
        const int2 a = rw[s];
        acc += H[(size_t)a.x * 64 + lane] * __int_as_float(a.y);
    }
    AGG[(size_t)d * 64 + lane] = acc;
}

// ---- combine: x7 = x5 + relu(agg2+cb2); out = x7.fc2w + fc2b + c3b; h3 = x7.c3w ----
__global__ __launch_bounds__(256) void k_combine(const float* __restrict__ X5,
                                                 const float* __restrict__ AGG2,
                                                 const float* __restrict__ CB2,
                                                 const float* __restrict__ FC2W,
                                                 const float* __restrict__ FC2B,
                                                 const float* __restrict__ C3W,
                                                 const float* __restrict__ C3B,
                                                 float* __restrict__ H3,
                                                 float* __restrict__ OUT, int N) {
    const int lane = threadIdx.x & 63;
    const int n = blockIdx.x * 4 + (threadIdx.x >> 6);
    if (n >= N) return;
    const size_t o = (size_t)n * 64 + lane;
    const float v = X5[o] + relu(AGG2[o] + CB2[lane]);
    float p9 = v * FC2W[lane];
    float p10 = v * C3W[lane];
#pragma unroll
    for (int s = 32; s >= 1; s >>= 1) {
        p9 += __shfl_xor(p9, s, 64);
        p10 += __shfl_xor(p10, s, 64);
    }
    if (lane == 0) {
        OUT[n] = p9 + FC2B[0] + C3B[0];
        H3[n] = p10;
    }
}

// ---- final CSR gather, 1 feature ----
__global__ __launch_bounds__(256) void k_gather1f(const int* __restrict__ start,
                                                  const int* __restrict__ degi,
                                                  const int2* __restrict__ rw,
                                                  const float* __restrict__ H3,
                                                  float* __restrict__ OUT, int N) {
    const int d = blockIdx.x * 256 + threadIdx.x;
    if (d >= N) return;
    int s = start[d];
    const int e2 = s + degi[d];
    float acc = 0.f;
    for (; s + 1 < e2; s += 2) {
        const int2 a = rw[s], b = rw[s + 1];
        acc += H3[a.x] * __int_as_float(a.y);
        acc += H3[b.x] * __int_as_float(b.y);
    }
    if (s < e2) {
        const int2 a = rw[s];
        acc += H3[a.x] * __int_as_float(a.y);
    }
    OUT[d] += acc;
}

extern "C" void kernel_launch(void* const* d_in, const int* in_sizes, int n_in,
                              void* d_out, int out_size, void* d_ws, size_t ws_size,
                              hipStream_t stream) {
    const float* x    = (const float*)d_in[0];
    const float* fcw  = (const float*)d_in[1];
    const float* fcb  = (const float*)d_in[2];
    const float* c1w  = (const float*)d_in[3];
    const float* c1b  = (const float*)d_in[4];
    const float* f1w  = (const float*)d_in[5];
    const float* f1b  = (const float*)d_in[6];
    const float* c2w  = (const float*)d_in[7];
    const float* c2b  = (const float*)d_in[8];
    const float* f2w  = (const float*)d_in[9];
    const float* f2b  = (const float*)d_in[10];
    const float* c3w  = (const float*)d_in[11];
    const float* c3b  = (const float*)d_in[12];
    const int*   ei   = (const int*)d_in[13];

    const int N = in_sizes[0] / IN_DIM;
    const int E = in_sizes[13] / 2;
    const int* row = ei;
    const int* col = ei + E;
    float* out = (float*)d_out;

    const size_t Npad = ((size_t)N + 127) & ~(size_t)127;
    const size_t Epad = ((size_t)E + 127) & ~(size_t)127;
    const size_t NF = (size_t)N * 64;
    int*   degi   = (int*)d_ws;                    // N
    float* dinv   = (float*)(degi + Npad);         // N
    int*   start  = (int*)(dinv + Npad);           // N
    int*   cursor = start + Npad;                  // N
    int*   bsum   = cursor + Npad;                 // 512
    int2*  rw     = (int2*)(bsum + 512);           // E (8B packed row+norm)
    float* x1     = (float*)(rw + Epad);           // N*64
    float* h1     = x1 + NF;                       // N*64
    float* agg1   = h1 + NF;                       // N*64
    float* x5     = agg1 + NF;                     // N*64
    float* h2     = h1;    // h1 dead after gather1
    float* agg2   = x1;    // x1 dead after gemm2
    float* h3     = agg1;  // agg1 dead after gemm2

    const int gE = (E + 255) / 256;
    const int gN = (N + 255) / 256;
    const int NB = (N + 255) / 256;
    const int gG = (N + BN - 1) / BN;
    const int gW = (N + 3) / 4;
    const int RB = (N + 7) / 8;
    const int nchunks = (E + CH - 1) / CH;

    // --- CSR build ---
    hipMemsetAsync(degi, 0, (size_t)N * sizeof(int), stream);
    k_deg<<<gE, 256, 0, stream>>>(col, degi, E);
    k_scan1<<<NB, 256, 0, stream>>>(degi, dinv, start, bsum, N);
    k_scan2<<<1, 512, 0, stream>>>(bsum, NB);
    k_scan3<<<NB, 256, 0, stream>>>(start, bsum, cursor, N);
    k_bucket<<<nchunks * 8, 256, 0, stream>>>(row, col, dinv, cursor, rw, E, RB, N);

    // --- layer 1 ---
    k_gemm<1><<<gG, 256, 0, stream>>>(x, nullptr, nullptr, fcw, c1w, fcb, x1, h1, N);
    k_gather64<<<gW, 256, 0, stream>>>(start, degi, rw, h1, agg1, N);

    // --- layer 2 ---
    k_gemm<2><<<gG, 256, 0, stream>>>(x1, agg1, c1b, f1w, c2w, f1b, x5, h2, N);
    k_gather64<<<gW, 256, 0, stream>>>(start, degi, rw, h2, agg2, N);

    // --- layer 3 ---
    k_combine<<<gW, 256, 0, stream>>>(x5, agg2, c2b, f2w, f2b, c3w, c3b, h3, out, N);
    k_gather1f<<<gN, 256, 0, stream>>>(start, degi, rw, h3, out, N);
}